// Round 1
// baseline (224.145 us; speedup 1.0000x reference)
//
#include <hip/hip_runtime.h>

#define JTOT  16384
#define BATCH 32
#define DD    32      // D
#define AE    16
#define HH    128     // H
#define EHD   256     // EH
#define LATD  32      // LAT
#define JT    32      // j-tile per block
#define LSTR  129     // LDS stride for base (129 % 32 == 1 -> conflict-free)
#define EPSV  1e-5f

// ---------------------------------------------------------------------------
// Kernel 1: per-(b,j) rows. Block = 32 j's x 32 b's = 1024 threads.
// base[j] (the b-independent part of the first linear layer) is computed once
// per block into LDS and shared by all 32 batches.
// ---------------------------------------------------------------------------
__global__ __launch_bounds__(1024) void k_rows(
    const float* __restrict__ x,       // [B, J]
    const int*   __restrict__ mask,    // [B, J]
    const int*   __restrict__ aidx,    // [J]
    const float* __restrict__ F,       // [J, D]
    const float* __restrict__ AeE,     // [A, Ae]
    const float* __restrict__ hW1,     // [49, H]
    const float* __restrict__ hb1,     // [H]
    const float* __restrict__ hg1,     // [H]
    const float* __restrict__ hB1,     // [H]
    const float* __restrict__ hW2,     // [H, D]
    const float* __restrict__ hb2,     // [D]
    const float* __restrict__ hg2,     // [D]
    const float* __restrict__ hB2,     // [D]
    float* __restrict__ partial,       // [nblk, 32, 32]
    float* __restrict__ pcnt)          // [nblk, 32]
{
    __shared__ float base[JT * LSTR];
    const int tid = threadIdx.x;
    const int j0  = blockIdx.x * JT;

    // ---- base[jj][t] = hb1[t] + F[j]. hW1[1..32][t] + AeE[a[j]]. hW1[33..48][t]
    for (int q = 0; q < JT * HH; q += 1024) {
        int o  = q + tid;
        int jj = o >> 7;
        int t  = o & (HH - 1);
        int j  = j0 + jj;
        const float* Fj = F + j * DD;
        const float* Aj = AeE + aidx[j] * AE;
        float acc = hb1[t];
        #pragma unroll
        for (int i = 0; i < DD; ++i) acc = fmaf(Fj[i], hW1[(1 + i) * HH + t], acc);
        #pragma unroll
        for (int i = 0; i < AE; ++i) acc = fmaf(Aj[i], hW1[(33 + i) * HH + t], acc);
        base[jj * LSTR + t] = acc;
    }
    __syncthreads();

    const int b  = tid >> 5;
    const int jj = tid & 31;
    const int j  = j0 + jj;
    const float xv = x[b * JTOT + j];
    const float mf = (float)mask[b * JTOT + j];
    const float* bj = base + jj * LSTR;

    // ---- LN stats over h1 (pass A; recompute v in pass B to keep VGPRs low)
    float sum = 0.f, ssq = 0.f;
    #pragma unroll 8
    for (int k = 0; k < HH; ++k) {
        float v = fmaf(xv, hW1[k], bj[k]);     // hW1 row 0 = w0
        sum += v;
        ssq  = fmaf(v, v, ssq);
    }
    float mu1  = sum * (1.f / HH);
    float var1 = ssq * (1.f / HH) - mu1 * mu1;
    float rs1  = rsqrtf(var1 + EPSV);

    // ---- pass B: h1 -> LN -> relu -> @ hW2 (wave-uniform scalar W2 reads)
    float acc[DD];
    #pragma unroll
    for (int d = 0; d < DD; ++d) acc[d] = 0.f;

    #pragma unroll 2
    for (int k = 0; k < HH; ++k) {
        float v  = fmaf(xv, hW1[k], bj[k]);
        float t  = (v - mu1) * rs1;
        float hk = fmaf(t, hg1[k], hB1[k]);
        hk = fmaxf(hk, 0.f);
        const float* w = hW2 + k * DD;
        #pragma unroll
        for (int d = 0; d < DD; ++d) acc[d] = fmaf(hk, w[d], acc[d]);
    }

    // ---- + hb2, LN over 32 (in-thread), relu, mask
    float s2 = 0.f, q2 = 0.f;
    #pragma unroll
    for (int d = 0; d < DD; ++d) {
        float t = acc[d] + hb2[d];
        acc[d] = t;
        s2 += t;
        q2  = fmaf(t, t, q2);
    }
    float mu2  = s2 * (1.f / DD);
    float var2 = q2 * (1.f / DD) - mu2 * mu2;
    float rs2  = rsqrtf(var2 + EPSV);
    #pragma unroll
    for (int d = 0; d < DD; ++d) {
        float t = fmaf((acc[d] - mu2) * rs2, hg2[d], hB2[d]);
        acc[d] = fmaxf(t, 0.f) * mf;
    }

    // ---- reduce over the 32 jj-lanes that share b (consecutive lanes in wave)
    float mine = 0.f;
    #pragma unroll
    for (int d = 0; d < DD; ++d) {
        float v = acc[d];
        v += __shfl_xor(v, 1);
        v += __shfl_xor(v, 2);
        v += __shfl_xor(v, 4);
        v += __shfl_xor(v, 8);
        v += __shfl_xor(v, 16);
        if (jj == d) mine = v;     // thread jj keeps column d == jj
    }
    partial[(blockIdx.x * BATCH + b) * DD + jj] = mine;

    float cm = mf;
    cm += __shfl_xor(cm, 1);
    cm += __shfl_xor(cm, 2);
    cm += __shfl_xor(cm, 4);
    cm += __shfl_xor(cm, 8);
    cm += __shfl_xor(cm, 16);
    if (jj == 0) pcnt[blockIdx.x * BATCH + b] = cm;
}

// ---------------------------------------------------------------------------
// Kernel 2: per-b reduction of partials + encoder MLP. 32 blocks x 256 thr.
// ---------------------------------------------------------------------------
__global__ __launch_bounds__(256) void k_final(
    const float* __restrict__ partial, // [nblk, 32, 32]
    const float* __restrict__ pcnt,    // [nblk, 32]
    const float* __restrict__ eW1,     // [32, 256]
    const float* __restrict__ eb1, const float* __restrict__ eg1,
    const float* __restrict__ eB1,
    const float* __restrict__ eW2,     // [256, 64]
    const float* __restrict__ eb2, const float* __restrict__ eg2,
    const float* __restrict__ eB2,
    float* __restrict__ out,           // [2, 32, 32] (mu then logvar, flat)
    int nblk)
{
    const int b   = blockIdx.x;
    const int tid = threadIdx.x;

    __shared__ float red[8 * DD];
    __shared__ float cw[4], ws1[4], ws2[4];
    __shared__ float cS[DD];
    __shared__ float eS[EHD];

    // ---- pooled[b][d] = sum over nblk partials
    {
        const int d  = tid & 31;
        const int c8 = tid >> 5;
        float s = 0.f;
        for (int blk = c8; blk < nblk; blk += 8)
            s += partial[(blk * BATCH + b) * DD + d];
        red[c8 * DD + d] = s;
    }
    // ---- cnt[b]
    float cs = 0.f;
    for (int blk = tid; blk < nblk; blk += 256) cs += pcnt[blk * BATCH + b];
    #pragma unroll
    for (int m = 1; m < 64; m <<= 1) cs += __shfl_xor(cs, m);
    if ((tid & 63) == 0) cw[tid >> 6] = cs;
    __syncthreads();

    if (tid < DD) {
        float c = 0.f;
        #pragma unroll
        for (int i = 0; i < 8; ++i) c += red[i * DD + tid];
        float cnt = cw[0] + cw[1] + cw[2] + cw[3];
        cS[tid] = c / fmaxf(cnt, 1.f);
    }
    __syncthreads();

    // ---- e = relu(LN(c @ eW1 + eb1))  (256 wide, one element per thread)
    float e = eb1[tid];
    #pragma unroll
    for (int i = 0; i < DD; ++i) e = fmaf(cS[i], eW1[i * EHD + tid], e);

    float sum = e, ssq = e * e;
    #pragma unroll
    for (int m = 1; m < 64; m <<= 1) {
        sum += __shfl_xor(sum, m);
        ssq += __shfl_xor(ssq, m);
    }
    if ((tid & 63) == 0) { ws1[tid >> 6] = sum; ws2[tid >> 6] = ssq; }
    __syncthreads();
    float S1 = ws1[0] + ws1[1] + ws1[2] + ws1[3];
    float S2 = ws2[0] + ws2[1] + ws2[2] + ws2[3];
    float mu = S1 * (1.f / EHD);
    float var = S2 * (1.f / EHD) - mu * mu;
    float rs = rsqrtf(var + EPSV);
    eS[tid] = fmaxf(fmaf((e - mu) * rs, eg1[tid], eB1[tid]), 0.f);
    __syncthreads();

    // ---- ml = relu(LN(e @ eW2 + eb2)); split -> mu | logvar
    if (tid < 2 * LATD) {
        float ml = eb2[tid];
        #pragma unroll 8
        for (int i = 0; i < EHD; ++i) ml = fmaf(eS[i], eW2[i * (2 * LATD) + tid], ml);
        float s = ml, q = ml * ml;
        #pragma unroll
        for (int m = 1; m < 64; m <<= 1) {
            s += __shfl_xor(s, m);
            q += __shfl_xor(q, m);
        }
        float mu2 = s * (1.f / (2 * LATD));
        float var2 = q * (1.f / (2 * LATD)) - mu2 * mu2;
        float rs2 = rsqrtf(var2 + EPSV);
        float v = fmaxf(fmaf((ml - mu2) * rs2, eg2[tid], eB2[tid]), 0.f);
        if (tid < LATD) out[b * LATD + tid] = v;
        else            out[BATCH * LATD + b * LATD + (tid - LATD)] = v;
    }
}

extern "C" void kernel_launch(void* const* d_in, const int* in_sizes, int n_in,
                              void* d_out, int out_size, void* d_ws, size_t ws_size,
                              hipStream_t stream) {
    const float* x    = (const float*)d_in[0];
    const int*   mask = (const int*)  d_in[1];
    const int*   aidx = (const int*)  d_in[2];
    const float* F    = (const float*)d_in[3];
    const float* AeE  = (const float*)d_in[4];
    const float* hW1  = (const float*)d_in[5];
    const float* hb1  = (const float*)d_in[6];
    const float* hg1  = (const float*)d_in[7];
    const float* hB1  = (const float*)d_in[8];
    const float* hW2  = (const float*)d_in[9];
    const float* hb2  = (const float*)d_in[10];
    const float* hg2  = (const float*)d_in[11];
    const float* hB2  = (const float*)d_in[12];
    const float* eW1  = (const float*)d_in[13];
    const float* eb1  = (const float*)d_in[14];
    const float* eg1  = (const float*)d_in[15];
    const float* eB1  = (const float*)d_in[16];
    const float* eW2  = (const float*)d_in[17];
    const float* eb2  = (const float*)d_in[18];
    const float* eg2  = (const float*)d_in[19];
    const float* eB2  = (const float*)d_in[20];
    float* out = (float*)d_out;

    const int nblk = JTOT / JT;                 // 512
    float* partial = (float*)d_ws;              // nblk*32*32 floats = 2 MB
    float* pcnt    = partial + nblk * BATCH * DD; // nblk*32 floats

    k_rows<<<dim3(nblk), dim3(1024), 0, stream>>>(
        x, mask, aidx, F, AeE, hW1, hb1, hg1, hB1, hW2, hb2, hg2, hB2,
        partial, pcnt);
    k_final<<<dim3(BATCH), dim3(256), 0, stream>>>(
        partial, pcnt, eW1, eb1, eg1, eB1, eW2, eb2, eg2, eB2, out, nblk);
}

// Round 2
// 183.352 us; speedup vs baseline: 1.2225x; 1.2225x over previous
//
#include <hip/hip_runtime.h>
#include <hip/hip_bf16.h>

#define JTOT  16384
#define BATCH 32
#define DD    32
#define AE    16
#define HH    128
#define EHD   256
#define LATD  32
#define NBLK  512     // k_rows blocks; 32 j's each
#define EPSV  1e-5f

typedef __attribute__((ext_vector_type(8))) short short8;
typedef __attribute__((ext_vector_type(4))) float f32x4;

// LDS float offsets
#define OFF_BASE 0      // 32*132 = 4224 (also reused for pooled block-reduce)
#define OFF_XS   4224   // 32*33
#define OFF_MS   5280   // 32*33
#define OFF_W0   6336   // 128
#define OFF_G1   6464   // 128
#define OFF_B1   6592   // 128
#define OFF_S0   6720   // 32
#define OFF_S1   6752   // 32
#define OFF_C1   6784   // 32
#define OFF_MW   6816   // 2
#define LDS_FLOATS 6848

__device__ __forceinline__ unsigned pk2(float lo, float hi) {
    float2 f; f.x = lo; f.y = hi;
    __hip_bfloat162 h = __float22bfloat162_rn(f);
    unsigned u; __builtin_memcpy(&u, &h, 4);
    return u;
}

__device__ __forceinline__ float aelem(float base_, float wv, float gv, float Bv,
                                       float xr, float rsr, float ccr) {
    float v = fmaf(xr, wv, base_);      // h1 = base + x*w0
    float t = fmaf(v, rsr, ccr);        // (h1 - mu)*rs
    return fmaxf(fmaf(t, gv, Bv), 0.f); // relu(t*g + B)
}

// ---------------------------------------------------------------------------
// Kernel 1: 512 blocks x 256 threads. Block owns 32 j's; wave owns 8 j's.
// Per j: A-tile = 32 batches x K=128 (bf16), B = hW2 (bf16, in VGPRs),
// 16x16x32 MFMA x16 -> 32x32 h2 tile -> LN2+ReLU+mask -> pooled regs.
// ---------------------------------------------------------------------------
__global__ __launch_bounds__(256, 2) void k_rows(
    const float* __restrict__ x, const int* __restrict__ mask,
    const int* __restrict__ aidx, const float* __restrict__ F,
    const float* __restrict__ AeE, const float* __restrict__ hW1,
    const float* __restrict__ hb1, const float* __restrict__ hg1,
    const float* __restrict__ hB1, const float* __restrict__ hW2,
    const float* __restrict__ hb2, const float* __restrict__ hg2,
    const float* __restrict__ hB2, float* __restrict__ partial)
{
    __shared__ float smem[LDS_FLOATS];
    const int tid = threadIdx.x;
    const int j0  = blockIdx.x * 32;

    float* BASEp = smem + OFF_BASE;   // [32 j][132] (128 used, pad 4)
    float* XSp   = smem + OFF_XS;     // [32 b][33]
    float* MSp   = smem + OFF_MS;     // [32 b][33]
    float* W0p   = smem + OFF_W0;
    float* G1p   = smem + OFF_G1;
    float* B1p   = smem + OFF_B1;
    float* S0p   = smem + OFF_S0;
    float* S1p   = smem + OFF_S1;
    float* C1p   = smem + OFF_C1;
    float* MWp   = smem + OFF_MW;

    // ---- stage x, mask, LN1 params
    for (int o = tid; o < 1024; o += 256) {
        int b = o >> 5, jj = o & 31;
        XSp[b * 33 + jj] = x[b * JTOT + j0 + jj];
        MSp[b * 33 + jj] = (float)mask[b * JTOT + j0 + jj];
    }
    if (tid < HH) { W0p[tid] = hW1[tid]; G1p[tid] = hg1[tid]; B1p[tid] = hB1[tid]; }

    // ---- base[j][k] = hb1[k] + F[j].W1f + AeE[a[j]].W1a  (b-independent part)
    {
        const int kk = tid & 127;
        const int jh = tid >> 7;             // wave-uniform
        float w[48];
        #pragma unroll
        for (int i = 0; i < 48; ++i) w[i] = hW1[(1 + i) * HH + kk];
        const float hb1v = hb1[kk];
        #pragma unroll 2
        for (int r = 0; r < 16; ++r) {
            int jj = __builtin_amdgcn_readfirstlane(2 * r + jh);
            int j  = j0 + jj;
            const float4* Fj = (const float4*)(F + j * DD);
            const float4* Aj = (const float4*)(AeE + aidx[j] * AE);
            float acc = hb1v;
            #pragma unroll
            for (int i4 = 0; i4 < 8; ++i4) {
                float4 f = Fj[i4];
                acc = fmaf(f.x, w[i4 * 4 + 0], acc);
                acc = fmaf(f.y, w[i4 * 4 + 1], acc);
                acc = fmaf(f.z, w[i4 * 4 + 2], acc);
                acc = fmaf(f.w, w[i4 * 4 + 3], acc);
            }
            #pragma unroll
            for (int i4 = 0; i4 < 4; ++i4) {
                float4 a = Aj[i4];
                acc = fmaf(a.x, w[32 + i4 * 4 + 0], acc);
                acc = fmaf(a.y, w[32 + i4 * 4 + 1], acc);
                acc = fmaf(a.z, w[32 + i4 * 4 + 2], acc);
                acc = fmaf(a.w, w[32 + i4 * 4 + 3], acc);
            }
            BASEp[jj * 132 + kk] = acc;
        }
    }
    __syncthreads();

    // ---- per-j LN1 stat scalars: S0=mean(base), S1=mean(base^2), C1=mean(base*w0)
    {
        const int jj = tid >> 3, p = tid & 7;
        const float* bp = BASEp + jj * 132 + p * 16;
        const float* wp = W0p + p * 16;
        float s0 = 0.f, s1 = 0.f, c1 = 0.f;
        #pragma unroll
        for (int i = 0; i < 16; ++i) {
            float v = bp[i], wv = wp[i];
            s0 += v; s1 = fmaf(v, v, s1); c1 = fmaf(v, wv, c1);
        }
        #pragma unroll
        for (int m = 1; m < 8; m <<= 1) {
            s0 += __shfl_xor(s0, m); s1 += __shfl_xor(s1, m); c1 += __shfl_xor(c1, m);
        }
        if (p == 0) {
            S0p[jj] = s0 * (1.f / HH);
            S1p[jj] = s1 * (1.f / HH);
            C1p[jj] = c1 * (1.f / HH);
        }
    }
    if (tid < 64) {                       // mean(w0), mean(w0^2)
        float a = W0p[tid], b = W0p[64 + tid];
        float s = a + b, qq = fmaf(a, a, b * b);
        #pragma unroll
        for (int m = 1; m < 64; m <<= 1) { s += __shfl_xor(s, m); qq += __shfl_xor(qq, m); }
        if (tid == 0) { MWp[0] = s * (1.f / HH); MWp[1] = qq * (1.f / HH); }
    }
    __syncthreads();

    const int lane = tid & 63;
    const int n = lane & 15, q = lane >> 4;

    // ---- B fragments: hW2 (128x32) as bf16, B[k][col]: col=lane&15, k=q*8+i
    short8 Bf[4][2];
    #pragma unroll
    for (int s = 0; s < 4; ++s)
        #pragma unroll
        for (int cb = 0; cb < 2; ++cb) {
            union { short8 v; unsigned u[4]; } t;
            #pragma unroll
            for (int p2 = 0; p2 < 4; ++p2) {
                int k0 = 32 * s + 8 * q + 2 * p2;
                float lo = hW2[(k0    ) * DD + cb * 16 + n];
                float hi = hW2[(k0 + 1) * DD + cb * 16 + n];
                t.u[p2] = pk2(lo, hi);
            }
            Bf[s][cb] = t.v;
        }

    float hb2v[2], g2v[2], B2v[2];
    #pragma unroll
    for (int cb = 0; cb < 2; ++cb) {
        hb2v[cb] = hb2[cb * 16 + n];
        g2v[cb]  = hg2[cb * 16 + n];
        B2v[cb]  = hB2[cb * 16 + n];
    }
    const float mw0v = MWp[0], sw0v = MWp[1];

    f32x4 pool[2][2];
    #pragma unroll
    for (int R = 0; R < 2; ++R)
        #pragma unroll
        for (int cb = 0; cb < 2; ++cb)
            pool[R][cb] = (f32x4){0.f, 0.f, 0.f, 0.f};

    const int wslot = tid >> 6;
    #pragma unroll 1
    for (int jl = 0; jl < 8; ++jl) {
        const int jj = wslot * 8 + jl;
        const float x0 = XSp[n * 33 + jj];          // A rows R=0: b = n
        const float x1 = XSp[(16 + n) * 33 + jj];   // A rows R=1: b = 16+n
        const float S0 = S0p[jj], S1 = S1p[jj], C1 = C1p[jj];

        float mu0 = fmaf(x0, mw0v, S0);
        float e0  = fmaf(x0 * x0, sw0v, fmaf(2.f * x0, C1, S1));
        float rs0 = rsqrtf(fmaxf(e0 - mu0 * mu0, 0.f) + EPSV);
        float cc0 = -mu0 * rs0;
        float mu1 = fmaf(x1, mw0v, S0);
        float e1  = fmaf(x1 * x1, sw0v, fmaf(2.f * x1, C1, S1));
        float rs1 = rsqrtf(fmaxf(e1 - mu1 * mu1, 0.f) + EPSV);
        float cc1 = -mu1 * rs1;

        f32x4 a00 = {0.f,0.f,0.f,0.f}, a01 = {0.f,0.f,0.f,0.f};
        f32x4 a10 = {0.f,0.f,0.f,0.f}, a11 = {0.f,0.f,0.f,0.f};

        #pragma unroll
        for (int s = 0; s < 4; ++s) {
            const float* bp = BASEp + jj * 132 + 32 * s + 8 * q;
            float4 ba = *(const float4*)bp;
            float4 bb = *(const float4*)(bp + 4);
            const float* wp = W0p + 32 * s + 8 * q;
            float4 wa = *(const float4*)wp;
            float4 wb = *(const float4*)(wp + 4);
            const float* gp = G1p + 32 * s + 8 * q;
            float4 ga = *(const float4*)gp;
            float4 gb = *(const float4*)(gp + 4);
            const float* Bp = B1p + 32 * s + 8 * q;
            float4 Ca = *(const float4*)Bp;
            float4 Cb2 = *(const float4*)(Bp + 4);

            union { short8 v; unsigned u[4]; } A0, A1;
            A0.u[0] = pk2(aelem(ba.x, wa.x, ga.x, Ca.x,  x0, rs0, cc0),
                          aelem(ba.y, wa.y, ga.y, Ca.y,  x0, rs0, cc0));
            A0.u[1] = pk2(aelem(ba.z, wa.z, ga.z, Ca.z,  x0, rs0, cc0),
                          aelem(ba.w, wa.w, ga.w, Ca.w,  x0, rs0, cc0));
            A0.u[2] = pk2(aelem(bb.x, wb.x, gb.x, Cb2.x, x0, rs0, cc0),
                          aelem(bb.y, wb.y, gb.y, Cb2.y, x0, rs0, cc0));
            A0.u[3] = pk2(aelem(bb.z, wb.z, gb.z, Cb2.z, x0, rs0, cc0),
                          aelem(bb.w, wb.w, gb.w, Cb2.w, x0, rs0, cc0));
            A1.u[0] = pk2(aelem(ba.x, wa.x, ga.x, Ca.x,  x1, rs1, cc1),
                          aelem(ba.y, wa.y, ga.y, Ca.y,  x1, rs1, cc1));
            A1.u[1] = pk2(aelem(ba.z, wa.z, ga.z, Ca.z,  x1, rs1, cc1),
                          aelem(ba.w, wa.w, ga.w, Ca.w,  x1, rs1, cc1));
            A1.u[2] = pk2(aelem(bb.x, wb.x, gb.x, Cb2.x, x1, rs1, cc1),
                          aelem(bb.y, wb.y, gb.y, Cb2.y, x1, rs1, cc1));
            A1.u[3] = pk2(aelem(bb.z, wb.z, gb.z, Cb2.z, x1, rs1, cc1),
                          aelem(bb.w, wb.w, gb.w, Cb2.w, x1, rs1, cc1));

            a00 = __builtin_amdgcn_mfma_f32_16x16x32_bf16(A0.v, Bf[s][0], a00, 0, 0, 0);
            a01 = __builtin_amdgcn_mfma_f32_16x16x32_bf16(A0.v, Bf[s][1], a01, 0, 0, 0);
            a10 = __builtin_amdgcn_mfma_f32_16x16x32_bf16(A1.v, Bf[s][0], a10, 0, 0, 0);
            a11 = __builtin_amdgcn_mfma_f32_16x16x32_bf16(A1.v, Bf[s][1], a11, 0, 0, 0);
        }

        // epilogue: +hb2, LN over 32 cols (row = R*16 + q*4 + r), relu, mask, pool
        #pragma unroll
        for (int r = 0; r < 4; ++r) {
            float t0 = a00[r] + hb2v[0];
            float t1 = a01[r] + hb2v[1];
            float s  = t0 + t1, ss = fmaf(t0, t0, t1 * t1);
            #pragma unroll
            for (int m = 1; m < 16; m <<= 1) { s += __shfl_xor(s, m); ss += __shfl_xor(ss, m); }
            float mu  = s * (1.f / DD);
            float var = ss * (1.f / DD) - mu * mu;
            float rs  = rsqrtf(fmaxf(var, 0.f) + EPSV);
            float cc  = -mu * rs;
            float mv  = MSp[(q * 4 + r) * 33 + jj];
            pool[0][0][r] = fmaf(fmaxf(fmaf(fmaf(t0, rs, cc), g2v[0], B2v[0]), 0.f), mv, pool[0][0][r]);
            pool[0][1][r] = fmaf(fmaxf(fmaf(fmaf(t1, rs, cc), g2v[1], B2v[1]), 0.f), mv, pool[0][1][r]);

            float u0 = a10[r] + hb2v[0];
            float u1 = a11[r] + hb2v[1];
            float s2 = u0 + u1, ss2 = fmaf(u0, u0, u1 * u1);
            #pragma unroll
            for (int m = 1; m < 16; m <<= 1) { s2 += __shfl_xor(s2, m); ss2 += __shfl_xor(ss2, m); }
            float mu2  = s2 * (1.f / DD);
            float var2 = ss2 * (1.f / DD) - mu2 * mu2;
            float rsB  = rsqrtf(fmaxf(var2, 0.f) + EPSV);
            float ccB  = -mu2 * rsB;
            float mv1  = MSp[(16 + q * 4 + r) * 33 + jj];
            pool[1][0][r] = fmaf(fmaxf(fmaf(fmaf(u0, rsB, ccB), g2v[0], B2v[0]), 0.f), mv1, pool[1][0][r]);
            pool[1][1][r] = fmaf(fmaxf(fmaf(fmaf(u1, rsB, ccB), g2v[1], B2v[1]), 0.f), mv1, pool[1][1][r]);
        }
    }

    // ---- block reduce 4 waves' pooled tiles -> partial[blk][b][d]
    __syncthreads();
    #pragma unroll
    for (int R = 0; R < 2; ++R)
        #pragma unroll
        for (int cb = 0; cb < 2; ++cb)
            #pragma unroll
            for (int r = 0; r < 4; ++r) {
                int b = R * 16 + q * 4 + r, d = cb * 16 + n;
                smem[wslot * 1024 + b * 32 + d] = pool[R][cb][r];
            }
    __syncthreads();
    for (int o = tid; o < 1024; o += 256) {
        float sv = smem[o] + smem[1024 + o] + smem[2048 + o] + smem[3072 + o];
        partial[blockIdx.x * 1024 + o] = sv;
    }
}

// ---------------------------------------------------------------------------
// Kernel 2: per-b reduction + encoder MLP. 32 blocks x 256 threads.
// ---------------------------------------------------------------------------
__global__ __launch_bounds__(256) void k_final(
    const float* __restrict__ partial, const int* __restrict__ mask,
    const float* __restrict__ eW1,
    const float* __restrict__ eb1, const float* __restrict__ eg1,
    const float* __restrict__ eB1,
    const float* __restrict__ eW2,
    const float* __restrict__ eb2, const float* __restrict__ eg2,
    const float* __restrict__ eB2,
    float* __restrict__ out, int nblk)
{
    const int b   = blockIdx.x;
    const int tid = threadIdx.x;

    __shared__ float red[8 * DD];
    __shared__ float cw[4], ws1[4], ws2[4];
    __shared__ float cS[DD];
    __shared__ float eS[EHD];

    {
        const int d  = tid & 31;
        const int c8 = tid >> 5;
        float s = 0.f;
        for (int blk = c8; blk < nblk; blk += 8)
            s += partial[(blk * BATCH + b) * DD + d];
        red[c8 * DD + d] = s;
    }
    float cs = 0.f;
    for (int i = tid; i < JTOT; i += 256) cs += (float)mask[b * JTOT + i];
    #pragma unroll
    for (int m = 1; m < 64; m <<= 1) cs += __shfl_xor(cs, m);
    if ((tid & 63) == 0) cw[tid >> 6] = cs;
    __syncthreads();

    if (tid < DD) {
        float c = 0.f;
        #pragma unroll
        for (int i = 0; i < 8; ++i) c += red[i * DD + tid];
        float cnt = cw[0] + cw[1] + cw[2] + cw[3];
        cS[tid] = c / fmaxf(cnt, 1.f);
    }
    __syncthreads();

    float e = eb1[tid];
    #pragma unroll
    for (int i = 0; i < DD; ++i) e = fmaf(cS[i], eW1[i * EHD + tid], e);

    float sum = e, ssq = e * e;
    #pragma unroll
    for (int m = 1; m < 64; m <<= 1) { sum += __shfl_xor(sum, m); ssq += __shfl_xor(ssq, m); }
    if ((tid & 63) == 0) { ws1[tid >> 6] = sum; ws2[tid >> 6] = ssq; }
    __syncthreads();
    float S1 = ws1[0] + ws1[1] + ws1[2] + ws1[3];
    float S2 = ws2[0] + ws2[1] + ws2[2] + ws2[3];
    float mu = S1 * (1.f / EHD);
    float var = S2 * (1.f / EHD) - mu * mu;
    float rs = rsqrtf(var + EPSV);
    eS[tid] = fmaxf(fmaf((e - mu) * rs, eg1[tid], eB1[tid]), 0.f);
    __syncthreads();

    if (tid < 2 * LATD) {
        float ml = eb2[tid];
        #pragma unroll 8
        for (int i = 0; i < EHD; ++i) ml = fmaf(eS[i], eW2[i * (2 * LATD) + tid], ml);
        float s = ml, qv = ml * ml;
        #pragma unroll
        for (int m = 1; m < 64; m <<= 1) { s += __shfl_xor(s, m); qv += __shfl_xor(qv, m); }
        float mu2 = s * (1.f / (2 * LATD));
        float var2 = qv * (1.f / (2 * LATD)) - mu2 * mu2;
        float rs2 = rsqrtf(var2 + EPSV);
        float v = fmaxf(fmaf((ml - mu2) * rs2, eg2[tid], eB2[tid]), 0.f);
        if (tid < LATD) out[b * LATD + tid] = v;
        else            out[BATCH * LATD + b * LATD + (tid - LATD)] = v;
    }
}

extern "C" void kernel_launch(void* const* d_in, const int* in_sizes, int n_in,
                              void* d_out, int out_size, void* d_ws, size_t ws_size,
                              hipStream_t stream) {
    const float* x    = (const float*)d_in[0];
    const int*   mask = (const int*)  d_in[1];
    const int*   aidx = (const int*)  d_in[2];
    const float* F    = (const float*)d_in[3];
    const float* AeE  = (const float*)d_in[4];
    const float* hW1  = (const float*)d_in[5];
    const float* hb1  = (const float*)d_in[6];
    const float* hg1  = (const float*)d_in[7];
    const float* hB1  = (const float*)d_in[8];
    const float* hW2  = (const float*)d_in[9];
    const float* hb2  = (const float*)d_in[10];
    const float* hg2  = (const float*)d_in[11];
    const float* hB2  = (const float*)d_in[12];
    const float* eW1  = (const float*)d_in[13];
    const float* eb1  = (const float*)d_in[14];
    const float* eg1  = (const float*)d_in[15];
    const float* eB1  = (const float*)d_in[16];
    const float* eW2  = (const float*)d_in[17];
    const float* eb2  = (const float*)d_in[18];
    const float* eg2  = (const float*)d_in[19];
    const float* eB2  = (const float*)d_in[20];
    float* out = (float*)d_out;

    float* partial = (float*)d_ws;  // NBLK*32*32 floats = 2 MB

    k_rows<<<dim3(NBLK), dim3(256), 0, stream>>>(
        x, mask, aidx, F, AeE, hW1, hb1, hg1, hB1, hW2, hb2, hg2, hB2, partial);
    k_final<<<dim3(BATCH), dim3(256), 0, stream>>>(
        partial, mask, eW1, eb1, eg1, eB1, eW2, eb2, eg2, eB2, out, NBLK);
}